// Round 1
// baseline (1012.851 us; speedup 1.0000x reference)
//
#include <hip/hip_runtime.h>
#include <math.h>

// Problem constants (fixed by reference setup_inputs)
constexpr int NB    = 16;
constexpr int NT    = 512;
constexpr int NF    = 256;
constexpr int NMIC  = 4;
constexpr int NELE  = 37;
constexpr int NAZI  = 73;
constexpr int MROWS = NB * NT;        // 8192
constexpr int KDIM  = NF * NMIC;      // 1024
constexpr int NCAND = NELE * NAZI;    // 2701
constexpr float SCALE = 2.0f / (float)KDIM;   // 2/(nmic*nf)

#define TILE 64
#define BKK  16
#define LDSP 68   // row stride (floats): 68*4B = 272B = 17*16B -> float4-aligned rows,
                  // and write pattern (4*kk + m) % 32 lands exactly 2 lanes/bank (free)

// C[M x N] = A[M x K] * B[N x K]^T * scale    (row-major, K = KDIM = 1024)
__global__ __launch_bounds__(256)
void sgemm_nt_kernel(const float* __restrict__ A, const float* __restrict__ B,
                     float* __restrict__ C, int M, int N, float scale)
{
    __shared__ __align__(16) float As[BKK][LDSP];
    __shared__ __align__(16) float Bs[BKK][LDSP];

    const int tid  = threadIdx.x;
    const int tx   = tid & 15;        // 0..15 -> output col group
    const int ty   = tid >> 4;        // 0..15 -> output row group
    const int row0 = blockIdx.y * TILE;
    const int col0 = blockIdx.x * TILE;

    // Staging: thread t loads one float4: tile row lm, k-offset lk0
    const int lm  = tid >> 2;          // 0..63
    const int lk0 = (tid & 3) * 4;     // 0,4,8,12
    const int ar  = row0 + lm;
    const int br  = col0 + lm;
    const bool av = (ar < M);
    const bool bv = (br < N);
    const float* aptr = A + (size_t)(av ? ar : 0) * KDIM + lk0;
    const float* bptr = B + (size_t)(bv ? br : 0) * KDIM + lk0;

    float acc[4][4] = {};

    for (int k0 = 0; k0 < KDIM; k0 += BKK) {
        float4 a4 = av ? *(const float4*)(aptr + k0) : make_float4(0.f, 0.f, 0.f, 0.f);
        float4 b4 = bv ? *(const float4*)(bptr + k0) : make_float4(0.f, 0.f, 0.f, 0.f);
        __syncthreads();   // previous iteration's reads complete before overwrite
        As[lk0 + 0][lm] = a4.x; As[lk0 + 1][lm] = a4.y;
        As[lk0 + 2][lm] = a4.z; As[lk0 + 3][lm] = a4.w;
        Bs[lk0 + 0][lm] = b4.x; Bs[lk0 + 1][lm] = b4.y;
        Bs[lk0 + 2][lm] = b4.z; Bs[lk0 + 3][lm] = b4.w;
        __syncthreads();
        #pragma unroll
        for (int k = 0; k < BKK; ++k) {
            float4 av4 = *(const float4*)(&As[k][ty * 4]);
            float4 bv4 = *(const float4*)(&Bs[k][tx * 4]);
            float am[4] = {av4.x, av4.y, av4.z, av4.w};
            float bm[4] = {bv4.x, bv4.y, bv4.z, bv4.w};
            #pragma unroll
            for (int i = 0; i < 4; ++i)
                #pragma unroll
                for (int j = 0; j < 4; ++j)
                    acc[i][j] = fmaf(am[i], bm[j], acc[i][j]);
        }
    }

    #pragma unroll
    for (int i = 0; i < 4; ++i) {
        int r = row0 + ty * 4 + i;
        if (r >= M) continue;
        #pragma unroll
        for (int j = 0; j < 4; ++j) {
            int c = col0 + tx * 4 + j;
            if (c < N) C[(size_t)r * N + c] = acc[i][j] * scale;
        }
    }
}

// Iteration 1: per (b,t) row argmax over pred_ss; ratio; write DOA/VAD slot s=0.
__global__ __launch_bounds__(256)
void argmax_iter1(const float* __restrict__ ss, const float* __restrict__ G,
                  const float* __restrict__ ele_c, const float* __restrict__ azi_c,
                  float* __restrict__ out_doa, float* __restrict__ out_vad,
                  int* __restrict__ idx1, float* __restrict__ ratio1)
{
    const int row = blockIdx.x;
    const int tid = threadIdx.x;
    const float* srow = ss + (size_t)row * NCAND;

    float best = -INFINITY; int bi = NCAND;
    for (int c = tid; c < NCAND; c += 256) {
        float v = srow[c];
        if (v > best) { best = v; bi = c; }
    }
    __shared__ float sv[256];
    __shared__ int   si[256];
    sv[tid] = best; si[tid] = bi;
    __syncthreads();
    for (int s = 128; s > 0; s >>= 1) {
        if (tid < s) {
            float v2 = sv[tid + s]; int i2 = si[tid + s];
            if (v2 > sv[tid] || (v2 == sv[tid] && i2 < si[tid])) { sv[tid] = v2; si[tid] = i2; }
        }
        __syncthreads();
    }
    if (tid == 0) {
        int idx = si[0]; float maxv = sv[0];
        float den = G[(size_t)idx * NCAND + idx];
        float ratio = maxv / (SCALE * den);       // num = maxv/SCALE
        int ei = idx / NAZI;
        int ai = idx - ei * NAZI;
        out_doa[((size_t)row * 2 + 0) * 2 + 0] = ele_c[ei];
        out_doa[((size_t)row * 2 + 1) * 2 + 0] = azi_c[ai];
        out_vad[(size_t)row * 2 + 0] = ratio;
        idx1[row] = idx; ratio1[row] = ratio;
    }
}

// Iteration 2: scores2[c] = ss[c] - ratio1*SCALE*G[idx1, c]; argmax; DOA/VAD slot s=1.
__global__ __launch_bounds__(256)
void argmax_iter2(const float* __restrict__ ss, const float* __restrict__ G,
                  const float* __restrict__ ele_c, const float* __restrict__ azi_c,
                  float* __restrict__ out_doa, float* __restrict__ out_vad,
                  const int* __restrict__ idx1, const float* __restrict__ ratio1)
{
    const int row = blockIdx.x;
    const int tid = threadIdx.x;
    const float* srow = ss + (size_t)row * NCAND;
    const float rs = ratio1[row] * SCALE;
    const float* grow = G + (size_t)idx1[row] * NCAND;

    float best = -INFINITY; int bi = NCAND;
    for (int c = tid; c < NCAND; c += 256) {
        float v = fmaf(-rs, grow[c], srow[c]);
        if (v > best) { best = v; bi = c; }
    }
    __shared__ float sv[256];
    __shared__ int   si[256];
    sv[tid] = best; si[tid] = bi;
    __syncthreads();
    for (int s = 128; s > 0; s >>= 1) {
        if (tid < s) {
            float v2 = sv[tid + s]; int i2 = si[tid + s];
            if (v2 > sv[tid] || (v2 == sv[tid] && i2 < si[tid])) { sv[tid] = v2; si[tid] = i2; }
        }
        __syncthreads();
    }
    if (tid == 0) {
        int idx = si[0]; float maxv = sv[0];
        float den = G[(size_t)idx * NCAND + idx];
        float ratio = maxv / (SCALE * den);
        int ei = idx / NAZI;
        int ai = idx - ei * NAZI;
        out_doa[((size_t)row * 2 + 0) * 2 + 1] = ele_c[ei];
        out_doa[((size_t)row * 2 + 1) * 2 + 1] = azi_c[ai];
        out_vad[(size_t)row * 2 + 1] = ratio;
    }
}

extern "C" void kernel_launch(void* const* d_in, const int* in_sizes, int n_in,
                              void* d_out, int out_size, void* d_ws, size_t ws_size,
                              hipStream_t stream)
{
    const float* ipd   = (const float*)d_in[0];   // [16,512,256,4] -> [8192,1024]
    const float* tmpl  = (const float*)d_in[1];   // [37,73,256,4]  -> [2701,1024]
    const float* ele_c = (const float*)d_in[2];   // [37]
    const float* azi_c = (const float*)d_in[3];   // [73]

    float* out     = (float*)d_out;
    float* out_doa = out;                                      // [8192,2,2]
    float* out_vad = out + (size_t)MROWS * 4;                  // [8192,2]
    float* out_ss  = out + (size_t)MROWS * 4 + (size_t)MROWS * 2; // [8192,2701]

    float* G      = (float*)d_ws;                              // [2701,2701]
    int*   idx1   = (int*)(G + (size_t)NCAND * NCAND);
    float* ratio1 = (float*)(idx1 + MROWS);

    dim3 blk(256);

    // pred_ss (also iteration-1 scores)
    dim3 g1((NCAND + TILE - 1) / TILE, MROWS / TILE);
    hipLaunchKernelGGL(sgemm_nt_kernel, g1, blk, 0, stream,
                       ipd, tmpl, out_ss, MROWS, NCAND, SCALE);

    // Gram matrix G = tmpl * tmpl^T  (unscaled)
    dim3 g2((NCAND + TILE - 1) / TILE, (NCAND + TILE - 1) / TILE);
    hipLaunchKernelGGL(sgemm_nt_kernel, g2, blk, 0, stream,
                       tmpl, tmpl, G, NCAND, NCAND, 1.0f);

    hipLaunchKernelGGL(argmax_iter1, dim3(MROWS), blk, 0, stream,
                       out_ss, G, ele_c, azi_c, out_doa, out_vad, idx1, ratio1);

    hipLaunchKernelGGL(argmax_iter2, dim3(MROWS), blk, 0, stream,
                       out_ss, G, ele_c, azi_c, out_doa, out_vad, idx1, ratio1);
}

// Round 3
// 359.368 us; speedup vs baseline: 2.8184x; 2.8184x over previous
//
#include <hip/hip_runtime.h>
#include <math.h>

typedef _Float16 f16;
typedef __attribute__((ext_vector_type(8))) _Float16 f16x8;
typedef __attribute__((ext_vector_type(4))) float    f32x4;
typedef __attribute__((address_space(3))) unsigned int       as3u32;
typedef const __attribute__((address_space(1))) unsigned int as1u32;

constexpr int NB=16, NT=512, NF=256, NMIC=4, NELE=37, NAZI=73;
constexpr int MROWS = NB*NT;     // 8192
constexpr int KDIM  = NF*NMIC;   // 1024
constexpr int NCAND = NELE*NAZI; // 2701
constexpr int NPAD  = 2816;      // padded candidate rows (22*128)
constexpr float SCALE = 2.0f / (float)KDIM;

constexpr size_t align256(size_t x){ return (x + 255) & ~(size_t)255; }
constexpr size_t G_BYTES = (size_t)NCAND*NCAND*4;          // 29.18 MB
constexpr size_t IDX_OFF = align256(G_BYTES);
constexpr size_t RAT_OFF = IDX_OFF + (size_t)MROWS*4;
constexpr size_t AHI_OFF = align256(RAT_OFF + (size_t)MROWS*4);
constexpr size_t A_BYTES = (size_t)MROWS*KDIM*2;           // 16.78 MB
constexpr size_t ALO_OFF = AHI_OFF + A_BYTES;
constexpr size_t BHI_OFF = ALO_OFF + A_BYTES;
constexpr size_t B_BYTES = (size_t)NPAD*KDIM*2;            // 5.77 MB
constexpr size_t BLO_OFF = BHI_OFF + B_BYTES;
constexpr size_t WS_FAST = BLO_OFF + B_BYTES;              // ~74.4 MB
constexpr size_t WS_FB   = RAT_OFF + (size_t)MROWS*4;      // ~29.25 MB

// ---------------- pre-pass: split f32 -> (hi, lo*2^11) f16 limbs ----------------
__global__ __launch_bounds__(256)
void split_kernel(const float* __restrict__ src, f16* __restrict__ hi, f16* __restrict__ lo,
                  long nsrc, long ntot)
{
    long i = ((long)blockIdx.x*256 + threadIdx.x)*8;
    if (i >= ntot) return;
    f16x8 h, l;
    if (i < nsrc) {
        float4 x0 = *(const float4*)(src + i);
        float4 x1 = *(const float4*)(src + i + 4);
        float xs[8] = {x0.x,x0.y,x0.z,x0.w,x1.x,x1.y,x1.z,x1.w};
        #pragma unroll
        for (int j=0;j<8;++j){
            f16 hh = (f16)xs[j];
            float r = (xs[j] - (float)hh) * 2048.0f;
            h[j] = hh; l[j] = (f16)r;
        }
    } else {
        #pragma unroll
        for (int j=0;j<8;++j){ h[j]=(f16)0.0f; l[j]=(f16)0.0f; }
    }
    *(f16x8*)(hi + i) = h;
    *(f16x8*)(lo + i) = l;
}

// ---------------- split-f16 MFMA GEMM: C[M,N] = (A*B^T)*scale, K=1024 ----------------
// A limbs: [M,1024] f16, B limbs: [NPAD,1024] f16 (rows >= tile reach, zero-padded)
#define BM 128
#define BN 64
#define BK 64

__global__ __launch_bounds__(256, 3)
void gemm_f16split_nt(const f16* __restrict__ Ahi, const f16* __restrict__ Alo,
                      const f16* __restrict__ Bhi, const f16* __restrict__ Blo,
                      float* __restrict__ C, int M, int N, float scale)
{
    __shared__ __align__(16) f16 sAhi[BM*BK];   // 16 KB, rows = 128B (8 granules of 16B)
    __shared__ __align__(16) f16 sAlo[BM*BK];
    __shared__ __align__(16) f16 sBhi[BN*BK];   // 8 KB
    __shared__ __align__(16) f16 sBlo[BN*BK];

    const int tid  = threadIdx.x;
    const int wid  = tid >> 6;
    const int lane = tid & 63;
    const int wr   = wid >> 1;        // 0..1 : wave row (64 rows)
    const int wc   = wid & 1;         // 0..1 : wave col (32 cols)

    // XCD-aware block swizzle (bijective only when nwg%8==0; else identity)
    int gx = gridDim.x, gy = gridDim.y;
    int nwg = gx*gy;
    int orig = blockIdx.x + gx*blockIdx.y;
    int wg = orig;
    if ((nwg & 7) == 0) wg = (orig & 7)*(nwg >> 3) + (orig >> 3);
    const int row0 = (wg / gx) * BM;
    const int col0 = (wg % gx) * BN;

    // staging lane geometry: 1024B per wave-call = 8 rows x 128B; granule swizzle g ^= row&7
    const int lrow = lane >> 3;       // 0..7
    const int lg   = lane & 7;        // dest granule
    const int sg   = lg ^ lrow;       // source granule (base rows are multiples of 8)

    // ds_read offsets (f16 elements), swizzled
    int aoff[4][2], boff[2][2];
    #pragma unroll
    for (int fi=0; fi<4; ++fi){
        int ra = wr*64 + fi*16 + (lane & 15);
        #pragma unroll
        for (int ks=0; ks<2; ++ks){
            int g = ks*4 + (lane >> 4);
            aoff[fi][ks] = ra*64 + ((g ^ (ra & 7)) * 8);
        }
    }
    #pragma unroll
    for (int fj=0; fj<2; ++fj){
        int rb = wc*32 + fj*16 + (lane & 15);
        #pragma unroll
        for (int ks=0; ks<2; ++ks){
            int g = ks*4 + (lane >> 4);
            boff[fj][ks] = rb*64 + ((g ^ (rb & 7)) * 8);
        }
    }

    f32x4 acc0[4][2], acc1[4][2];
    #pragma unroll
    for (int i=0;i<4;++i)
        #pragma unroll
        for (int j=0;j<2;++j){
            acc0[i][j] = (f32x4){0.f,0.f,0.f,0.f};
            acc1[i][j] = (f32x4){0.f,0.f,0.f,0.f};
        }

    for (int k0 = 0; k0 < KDIM; k0 += BK) {
        // ---- stage tiles (linear LDS dest, pre-swizzled global source) ----
        #pragma unroll
        for (int j=0; j<4; ++j){
            int r = (j*4 + wid)*8 + lrow;
            size_t so = (size_t)(row0 + r)*KDIM + k0 + sg*8;
            __builtin_amdgcn_global_load_lds((as1u32*)(Ahi + so),
                (as3u32*)(sAhi + (size_t)(j*4 + wid)*512), 16, 0, 0);
            __builtin_amdgcn_global_load_lds((as1u32*)(Alo + so),
                (as3u32*)(sAlo + (size_t)(j*4 + wid)*512), 16, 0, 0);
        }
        #pragma unroll
        for (int j=0; j<2; ++j){
            int r = (j*4 + wid)*8 + lrow;
            size_t so = (size_t)(col0 + r)*KDIM + k0 + sg*8;
            __builtin_amdgcn_global_load_lds((as1u32*)(Bhi + so),
                (as3u32*)(sBhi + (size_t)(j*4 + wid)*512), 16, 0, 0);
            __builtin_amdgcn_global_load_lds((as1u32*)(Blo + so),
                (as3u32*)(sBlo + (size_t)(j*4 + wid)*512), 16, 0, 0);
        }
        __syncthreads();   // drains vmcnt; tiles visible to all waves

        #pragma unroll
        for (int ks=0; ks<2; ++ks){
            f16x8 ah[4], al[4], bh[2], bl[2];
            #pragma unroll
            for (int fi=0; fi<4; ++fi){
                ah[fi] = *(const f16x8*)(sAhi + aoff[fi][ks]);
                al[fi] = *(const f16x8*)(sAlo + aoff[fi][ks]);
            }
            #pragma unroll
            for (int fj=0; fj<2; ++fj){
                bh[fj] = *(const f16x8*)(sBhi + boff[fj][ks]);
                bl[fj] = *(const f16x8*)(sBlo + boff[fj][ks]);
            }
            #pragma unroll
            for (int fi=0; fi<4; ++fi)
                #pragma unroll
                for (int fj=0; fj<2; ++fj){
                    acc0[fi][fj] = __builtin_amdgcn_mfma_f32_16x16x32_f16(ah[fi], bh[fj], acc0[fi][fj], 0,0,0);
                    acc1[fi][fj] = __builtin_amdgcn_mfma_f32_16x16x32_f16(ah[fi], bl[fj], acc1[fi][fj], 0,0,0);
                    acc1[fi][fj] = __builtin_amdgcn_mfma_f32_16x16x32_f16(al[fi], bh[fj], acc1[fi][fj], 0,0,0);
                }
        }
        __syncthreads();   // reads done before next-iter staging overwrites
    }

    // epilogue: combine limbs, scale, store (C/D layout: col=lane&15, row=(lane>>4)*4+e)
    #pragma unroll
    for (int fi=0; fi<4; ++fi){
        #pragma unroll
        for (int fj=0; fj<2; ++fj){
            int c = col0 + wc*32 + fj*16 + (lane & 15);
            if (c >= N) continue;
            #pragma unroll
            for (int e=0; e<4; ++e){
                int r = row0 + wr*64 + fi*16 + (lane >> 4)*4 + e;
                if (r < M)
                    C[(size_t)r*N + c] = (acc0[fi][fj][e] + acc1[fi][fj][e]*(1.0f/2048.0f))*scale;
            }
        }
    }
}

// ---------------- fallback f32 SGEMM (round-1, known-good) ----------------
#define TILE 64
#define BKK  16
#define LDSP 68

__global__ __launch_bounds__(256)
void sgemm_nt_kernel(const float* __restrict__ A, const float* __restrict__ B,
                     float* __restrict__ C, int M, int N, float scale)
{
    __shared__ __align__(16) float As[BKK][LDSP];
    __shared__ __align__(16) float Bs[BKK][LDSP];

    const int tid  = threadIdx.x;
    const int tx   = tid & 15;
    const int ty   = tid >> 4;
    const int row0 = blockIdx.y * TILE;
    const int col0 = blockIdx.x * TILE;

    const int lm  = tid >> 2;
    const int lk0 = (tid & 3) * 4;
    const int ar  = row0 + lm;
    const int br  = col0 + lm;
    const bool av = (ar < M);
    const bool bv = (br < N);
    const float* aptr = A + (size_t)(av ? ar : 0) * KDIM + lk0;
    const float* bptr = B + (size_t)(bv ? br : 0) * KDIM + lk0;

    float acc[4][4] = {};

    for (int k0 = 0; k0 < KDIM; k0 += BKK) {
        float4 a4 = av ? *(const float4*)(aptr + k0) : make_float4(0.f,0.f,0.f,0.f);
        float4 b4 = bv ? *(const float4*)(bptr + k0) : make_float4(0.f,0.f,0.f,0.f);
        __syncthreads();
        As[lk0+0][lm]=a4.x; As[lk0+1][lm]=a4.y; As[lk0+2][lm]=a4.z; As[lk0+3][lm]=a4.w;
        Bs[lk0+0][lm]=b4.x; Bs[lk0+1][lm]=b4.y; Bs[lk0+2][lm]=b4.z; Bs[lk0+3][lm]=b4.w;
        __syncthreads();
        #pragma unroll
        for (int k=0;k<BKK;++k){
            float4 av4 = *(const float4*)(&As[k][ty*4]);
            float4 bv4 = *(const float4*)(&Bs[k][tx*4]);
            float am[4]={av4.x,av4.y,av4.z,av4.w};
            float bm[4]={bv4.x,bv4.y,bv4.z,bv4.w};
            #pragma unroll
            for (int i=0;i<4;++i)
                #pragma unroll
                for (int j=0;j<4;++j)
                    acc[i][j] = fmaf(am[i], bm[j], acc[i][j]);
        }
    }
    #pragma unroll
    for (int i=0;i<4;++i){
        int r = row0 + ty*4 + i;
        if (r >= M) continue;
        #pragma unroll
        for (int j=0;j<4;++j){
            int c = col0 + tx*4 + j;
            if (c < N) C[(size_t)r*N + c] = acc[i][j]*scale;
        }
    }
}

// ---------------- argmax iterations: one wave per (b,t) row ----------------
__global__ __launch_bounds__(256)
void argmax1_kernel(const float* __restrict__ ss, const float* __restrict__ G,
                    const float* __restrict__ ele_c, const float* __restrict__ azi_c,
                    float* __restrict__ out_doa, float* __restrict__ out_vad,
                    int* __restrict__ idx1, float* __restrict__ ratio1)
{
    const int row  = blockIdx.x*4 + (threadIdx.x >> 6);
    const int lane = threadIdx.x & 63;
    const float* srow = ss + (size_t)row*NCAND;

    float best = -1e30f; int bi = 0x7fffffff;
    for (int c = lane; c < NCAND; c += 64){
        float v = srow[c];
        if (v > best){ best = v; bi = c; }
    }
    #pragma unroll
    for (int off=32; off; off>>=1){
        float v2 = __shfl_xor(best, off);
        int   i2 = __shfl_xor(bi, off);
        if (v2 > best || (v2 == best && i2 < bi)){ best = v2; bi = i2; }
    }
    if (lane == 0){
        float den   = G[(size_t)bi*NCAND + bi];
        float ratio = best / (SCALE*den);
        int ei = bi / NAZI, ai = bi - ei*NAZI;
        out_doa[((size_t)row*2 + 0)*2 + 0] = ele_c[ei];
        out_doa[((size_t)row*2 + 1)*2 + 0] = azi_c[ai];
        out_vad[(size_t)row*2 + 0] = ratio;
        idx1[row] = bi; ratio1[row] = ratio;
    }
}

__global__ __launch_bounds__(256)
void argmax2_kernel(const float* __restrict__ ss, const float* __restrict__ G,
                    const float* __restrict__ ele_c, const float* __restrict__ azi_c,
                    float* __restrict__ out_doa, float* __restrict__ out_vad,
                    const int* __restrict__ idx1, const float* __restrict__ ratio1)
{
    const int row  = blockIdx.x*4 + (threadIdx.x >> 6);
    const int lane = threadIdx.x & 63;
    const float* srow = ss + (size_t)row*NCAND;
    const float  rs   = ratio1[row] * SCALE;
    const float* grow = G + (size_t)idx1[row]*NCAND;

    float best = -1e30f; int bi = 0x7fffffff;
    for (int c = lane; c < NCAND; c += 64){
        float v = fmaf(-rs, grow[c], srow[c]);
        if (v > best){ best = v; bi = c; }
    }
    #pragma unroll
    for (int off=32; off; off>>=1){
        float v2 = __shfl_xor(best, off);
        int   i2 = __shfl_xor(bi, off);
        if (v2 > best || (v2 == best && i2 < bi)){ best = v2; bi = i2; }
    }
    if (lane == 0){
        float den   = G[(size_t)bi*NCAND + bi];
        float ratio = best / (SCALE*den);
        int ei = bi / NAZI, ai = bi - ei*NAZI;
        out_doa[((size_t)row*2 + 0)*2 + 1] = ele_c[ei];
        out_doa[((size_t)row*2 + 1)*2 + 1] = azi_c[ai];
        out_vad[(size_t)row*2 + 1] = ratio;
    }
}

// ---------------- launch ----------------
extern "C" void kernel_launch(void* const* d_in, const int* in_sizes, int n_in,
                              void* d_out, int out_size, void* d_ws, size_t ws_size,
                              hipStream_t stream)
{
    const float* ipd   = (const float*)d_in[0];   // [8192,1024]
    const float* tmpl  = (const float*)d_in[1];   // [2701,1024]
    const float* ele_c = (const float*)d_in[2];
    const float* azi_c = (const float*)d_in[3];

    float* out     = (float*)d_out;
    float* out_doa = out;                                         // [8192,2,2]
    float* out_vad = out + (size_t)MROWS*4;                       // [8192,2]
    float* out_ss  = out + (size_t)MROWS*4 + (size_t)MROWS*2;     // [8192,2701]

    char*  ws     = (char*)d_ws;
    float* G      = (float*)(ws);
    int*   idx1   = (int*)  (ws + IDX_OFF);
    float* ratio1 = (float*)(ws + RAT_OFF);

    dim3 blk(256);

    if (ws_size >= WS_FAST) {
        f16* Ahi = (f16*)(ws + AHI_OFF);
        f16* Alo = (f16*)(ws + ALO_OFF);
        f16* Bhi = (f16*)(ws + BHI_OFF);
        f16* Blo = (f16*)(ws + BLO_OFF);

        long nA = (long)MROWS*KDIM;
        long nBs = (long)NCAND*KDIM, nBt = (long)NPAD*KDIM;
        hipLaunchKernelGGL(split_kernel, dim3((unsigned)(nA/2048)), blk, 0, stream,
                           ipd, Ahi, Alo, nA, nA);
        hipLaunchKernelGGL(split_kernel, dim3((unsigned)(nBt/2048)), blk, 0, stream,
                           tmpl, Bhi, Blo, nBs, nBt);

        // pred_ss (iteration-1 scores): [8192 x 2701]
        hipLaunchKernelGGL(gemm_f16split_nt, dim3(43, 64), blk, 0, stream,
                           Ahi, Alo, Bhi, Blo, out_ss, MROWS, NCAND, SCALE);
        // Gram: [2701 x 2701], unscaled
        hipLaunchKernelGGL(gemm_f16split_nt, dim3(43, 22), blk, 0, stream,
                           Bhi, Blo, Bhi, Blo, G, NCAND, NCAND, 1.0f);
    } else {
        dim3 g1((NCAND + TILE - 1)/TILE, MROWS/TILE);
        hipLaunchKernelGGL(sgemm_nt_kernel, g1, blk, 0, stream,
                           ipd, tmpl, out_ss, MROWS, NCAND, SCALE);
        dim3 g2((NCAND + TILE - 1)/TILE, (NCAND + TILE - 1)/TILE);
        hipLaunchKernelGGL(sgemm_nt_kernel, g2, blk, 0, stream,
                           tmpl, tmpl, G, NCAND, NCAND, 1.0f);
    }

    hipLaunchKernelGGL(argmax1_kernel, dim3(MROWS/4), blk, 0, stream,
                       out_ss, G, ele_c, azi_c, out_doa, out_vad, idx1, ratio1);
    hipLaunchKernelGGL(argmax2_kernel, dim3(MROWS/4), blk, 0, stream,
                       out_ss, G, ele_c, azi_c, out_doa, out_vad, idx1, ratio1);
}